// Round 1
// baseline (225.232 us; speedup 1.0000x reference)
//
#include <hip/hip_runtime.h>
#include <math.h>

// Polynomial feature map: Xp = X @ P; out = [bias | Xp | Xp^2 | Xp^3 | pairs | sqrt(|Xp|+eps)]
// X: [16384, 2048] f32, P: [2048, 512] f32, out: [16384, 2561] f32.
// pairs (triu k=1, first 512): c<511 -> Xp[:,0]*Xp[:,c+1]; c==511 -> Xp[:,1]*Xp[:,2]

typedef __attribute__((ext_vector_type(4))) float f32x4;
typedef __attribute__((ext_vector_type(8))) short bf16x8;
typedef __attribute__((ext_vector_type(4))) short s16x4;

#define MM 16384
#define NN 512
#define KK 2048
#define OUTW 2561

#define BM 128
#define BN 128
#define BK 32
#define PAD 40  // LDS row pitch (elems): 80 B -> 16B-aligned khalf*16 offsets, 2-way-max bank pattern

__device__ __forceinline__ short f2bf(float x) {
  union { float f; unsigned u; } c; c.f = x;
  unsigned r = c.u + 0x7fffu + ((c.u >> 16) & 1u);  // round-to-nearest-even
  return (short)(r >> 16);
}

__global__ __launch_bounds__(256) void gemm_k(const float* __restrict__ A,
                                              const float* __restrict__ B,
                                              float* __restrict__ out) {
  __shared__ __align__(16) short As[BM][PAD];  // As[m][k] bf16
  __shared__ __align__(16) short Bs[BN][PAD];  // Bs[n][k] bf16 (B transposed at stage)

  const int tid = threadIdx.x;
  const int bx  = blockIdx.x;
  const int m0 = (bx >> 2) * BM;   // 128 row blocks
  const int n0 = (bx & 3) * BN;    // 4 col blocks
  const int wid = tid >> 6, lane = tid & 63;
  const int wr = wid >> 1, wc = wid & 1;     // 2x2 wave grid, 64x64 per wave
  const int lrow = lane & 15, kh = lane >> 4;

  f32x4 acc[4][4];
#pragma unroll
  for (int i = 0; i < 4; i++)
#pragma unroll
    for (int j = 0; j < 4; j++) acc[i][j] = (f32x4)0.0f;

  for (int k0 = 0; k0 < KK; k0 += BK) {
    // ---- stage A: 128x32 f32 -> bf16 LDS ----
#pragma unroll
    for (int i = 0; i < 4; i++) {
      int fid = i * 256 + tid;           // 1024 float4 tiles
      int ar = fid >> 3;                 // 8 float4 per row
      int ac = (fid & 7) << 2;
      f32x4 v = *(const f32x4*)(A + (size_t)(m0 + ar) * KK + (k0 + ac));
      s16x4 h;
      h[0] = f2bf(v[0]); h[1] = f2bf(v[1]); h[2] = f2bf(v[2]); h[3] = f2bf(v[3]);
      *(s16x4*)&As[ar][ac] = h;          // 8B aligned (80B pitch, ac*2 in {0,8,...,56})
    }
    // ---- stage B: 32x128 f32 -> bf16 LDS, transposed ----
#pragma unroll
    for (int i = 0; i < 4; i++) {
      int fid = i * 256 + tid;           // 1024 float4 tiles
      int br = fid >> 5;                 // 32 float4 per row (128 cols)
      int bc = (fid & 31) << 2;
      f32x4 v = *(const f32x4*)(B + (size_t)(k0 + br) * NN + (n0 + bc));
#pragma unroll
      for (int j = 0; j < 4; j++) Bs[bc + j][br] = f2bf(v[j]);
    }
    __syncthreads();

    // ---- fragments + MFMA ----
    bf16x8 af[4], bf[4];
#pragma unroll
    for (int m = 0; m < 4; m++)
      af[m] = *(const bf16x8*)&As[wr * 64 + m * 16 + lrow][kh * 8];
#pragma unroll
    for (int n = 0; n < 4; n++)
      bf[n] = *(const bf16x8*)&Bs[wc * 64 + n * 16 + lrow][kh * 8];
#pragma unroll
    for (int m = 0; m < 4; m++)
#pragma unroll
      for (int n = 0; n < 4; n++)
        acc[m][n] = __builtin_amdgcn_mfma_f32_16x16x32_bf16(af[m], bf[n], acc[m][n], 0, 0, 0);
    __syncthreads();
  }

  // ---- write Xp into p1 region of out (cols 1..512) ----
  // C/D layout: col = lane&15, row = (lane>>4)*4 + reg
#pragma unroll
  for (int m = 0; m < 4; m++) {
#pragma unroll
    for (int n = 0; n < 4; n++) {
#pragma unroll
      for (int r = 0; r < 4; r++) {
        int row = m0 + wr * 64 + m * 16 + kh * 4 + r;
        int col = n0 + wc * 64 + n * 16 + lrow;
        out[(size_t)row * OUTW + 1 + col] = acc[m][n][r];
      }
    }
  }
}

__global__ __launch_bounds__(512) void epi_k(float* __restrict__ out) {
  const int r = blockIdx.x;
  const int c = threadIdx.x;  // 0..511
  float* row = out + (size_t)r * OUTW;
  __shared__ float s[NN];
  float xp = row[1 + c];
  s[c] = xp;
  __syncthreads();
  float p2 = xp * xp;
  float p3 = p2 * xp;
  float sq = sqrtf(fabsf(xp) + 1e-8f);
  float pr = (c < 511) ? s[0] * s[c + 1] : s[1] * s[2];
  if (c == 0) row[0] = 1.0f;
  row[513 + c]  = p2;
  row[1025 + c] = p3;
  row[1537 + c] = pr;
  row[2049 + c] = sq;
}

extern "C" void kernel_launch(void* const* d_in, const int* in_sizes, int n_in,
                              void* d_out, int out_size, void* d_ws, size_t ws_size,
                              hipStream_t stream) {
  const float* X = (const float*)d_in[0];
  const float* P = (const float*)d_in[1];
  float* out = (float*)d_out;
  (void)d_ws; (void)ws_size; (void)in_sizes; (void)n_in; (void)out_size;

  gemm_k<<<dim3(512), dim3(256), 0, stream>>>(X, P, out);
  epi_k<<<dim3(MM), dim3(512), 0, stream>>>(out);
}

// Round 2
// 128.116 us; speedup vs baseline: 1.7580x; 1.7580x over previous
//
#include <hip/hip_runtime.h>
#include <math.h>

// Polynomial feature map: Xp = X @ P; out = [bias | Xp | Xp^2 | Xp^3 | pairs | sqrt(|Xp|+eps)]
// X: [16384, 2048] f32, P: [2048, 512] f32, out: [16384, 2561] f32.
// pairs (triu k=1, first 512): c<511 -> Xp[:,0]*Xp[:,c+1]; c==511 -> Xp[:,1]*Xp[:,2]
//
// Fast path: prep_b transposes+converts P -> Bt bf16 [512][2048] in d_ws, then fused_k
// (BM=64 x full-N=512, BK=32, double-buffered LDS, global_load_lds for B, fused epilogue).
// Fallback (ws too small): round-1 gemm_k + epi_k.

typedef __attribute__((ext_vector_type(4))) float f32x4;
typedef __attribute__((ext_vector_type(8))) short bf16x8;
typedef __attribute__((ext_vector_type(4))) short s16x4;

#define MM 16384
#define NN 512
#define KK 2048
#define OUTW 2561

#define BM 64
#define BK 32
#define NT (KK / BK)  // 64

__device__ __forceinline__ short f2bf(float x) {
  union { float f; unsigned u; } c; c.f = x;
  unsigned r = c.u + 0x7fffu + ((c.u >> 16) & 1u);  // round-to-nearest-even
  return (short)(r >> 16);
}

__device__ __forceinline__ void gl_lds16(const void* g, void* l) {
  __builtin_amdgcn_global_load_lds((const __attribute__((address_space(1))) unsigned int*)g,
                                   (__attribute__((address_space(3))) unsigned int*)l, 16, 0, 0);
}

// ---------------- prep: P [K][N] f32 -> Bt [N][K] bf16 ----------------
__global__ __launch_bounds__(256) void prep_b(const float* __restrict__ P, short* __restrict__ Bt) {
  __shared__ float ts[64][65];
  const int tid = threadIdx.x;
  const int k0 = (blockIdx.x >> 3) * 64;  // 32 k-blocks
  const int n0 = (blockIdx.x & 7) * 64;   // 8 n-blocks
#pragma unroll
  for (int j = 0; j < 16; ++j) {
    int idx = j * 256 + tid;
    int kr = idx >> 6, nc = idx & 63;
    ts[kr][nc] = P[(size_t)(k0 + kr) * NN + n0 + nc];
  }
  __syncthreads();
#pragma unroll
  for (int j = 0; j < 16; ++j) {
    int idx = j * 256 + tid;
    int nr = idx >> 6, kc = idx & 63;
    Bt[(size_t)(n0 + nr) * KK + k0 + kc] = f2bf(ts[kc][nr]);
  }
}

// ---------------- fused GEMM + polynomial epilogue ----------------
// LDS tiles: rows of 32 bf16 (64B). Swizzle: 16B-slot' = slot ^ ((row>>1)&3)
// (2-way max bank aliasing on ds_read_b128; 2-way is free per m136).
// B is written by global_load_lds (linear lane*16B dest), so the swizzle is
// realized by permuting the per-lane GLOBAL source k-slot (rule #21).
__global__ __launch_bounds__(512) void fused_k(const float* __restrict__ X,
                                               const short* __restrict__ Bt,
                                               float* __restrict__ out) {
  __shared__ short As[2][BM * BK];   // 4 KB each, swizzled [64][32]
  __shared__ short Bs[2][NN * BK];   // 32 KB each, swizzled [512][32]
  __shared__ float s012[3][BM];

  const int tid = threadIdx.x;
  const int wid = tid >> 6, lane = tid & 63;
  const int lrow = lane & 15, kh = lane >> 4;
  const int m0 = blockIdx.x * BM;

  // A staging: thread t -> row = t>>3, 4-float k-group = t&7 (one f32x4 per iter)
  const int arow = tid >> 3, akq = tid & 7;
  const int aoff = arow * 32 + ((((akq >> 1)) ^ ((arow >> 1) & 3)) << 3) + (akq & 1) * 4;  // shorts
  const float* aG = X + (size_t)(m0 + arow) * KK + akq * 4;

  // B staging: 4 rounds; round p, wave w covers rows n = (p*8+w)*16 .. +15
  const int kd = (lane & 3) ^ ((lane >> 3) & 3);  // pre-swizzled source k-slot
  const short* bG[4];
  int bOff[4];
#pragma unroll
  for (int p = 0; p < 4; ++p) {
    int nbase = (p * 8 + wid) * 16;
    bOff[p] = nbase * 32;  // shorts (64B rows, linear)
    bG[p] = Bt + (size_t)(nbase + (lane >> 2)) * KK + kd * 8;
  }

  f32x4 acc[4][4];
#pragma unroll
  for (int m = 0; m < 4; ++m)
#pragma unroll
    for (int n = 0; n < 4; ++n) acc[m][n] = (f32x4)0.0f;

  // ---- prologue: stage tile 0, prefetch A(1) ----
  f32x4 aR = *(const f32x4*)aG;
#pragma unroll
  for (int p = 0; p < 4; ++p) gl_lds16(bG[p], &Bs[0][bOff[p]]);
  {
    s16x4 h;
    h[0] = f2bf(aR[0]); h[1] = f2bf(aR[1]); h[2] = f2bf(aR[2]); h[3] = f2bf(aR[3]);
    *(s16x4*)&As[0][aoff] = h;
  }
  aR = *(const f32x4*)(aG + BK);
  __syncthreads();

  int cur = 0;
  for (int t = 0; t < NT; ++t) {
    if (t + 1 < NT) {
      // issue next-tile staging BEFORE compute (latency hides under MFMA; barrier drains it)
#pragma unroll
      for (int p = 0; p < 4; ++p) gl_lds16(bG[p] + (size_t)(t + 1) * BK, &Bs[cur ^ 1][bOff[p]]);
      s16x4 h;
      h[0] = f2bf(aR[0]); h[1] = f2bf(aR[1]); h[2] = f2bf(aR[2]); h[3] = f2bf(aR[3]);
      *(s16x4*)&As[cur ^ 1][aoff] = h;
      int t2 = (t + 2 < NT) ? t + 2 : t;  // clamp to stay in-bounds
      aR = *(const f32x4*)(aG + (size_t)t2 * BK);
    }
    // ---- fragments + MFMA from buf[cur] ----
    bf16x8 af[4], bfr[4];
#pragma unroll
    for (int m = 0; m < 4; ++m) {
      int r = m * 16 + lrow;
      af[m] = *(const bf16x8*)&As[cur][r * 32 + ((kh ^ ((r >> 1) & 3)) << 3)];
    }
#pragma unroll
    for (int n = 0; n < 4; ++n) {
      int r = wid * 64 + n * 16 + lrow;
      bfr[n] = *(const bf16x8*)&Bs[cur][r * 32 + ((kh ^ ((r >> 1) & 3)) << 3)];
    }
#pragma unroll
    for (int m = 0; m < 4; ++m)
#pragma unroll
      for (int n = 0; n < 4; ++n)
        acc[m][n] = __builtin_amdgcn_mfma_f32_16x16x32_bf16(af[m], bfr[n], acc[m][n], 0, 0, 0);
    __syncthreads();
    cur ^= 1;
  }

  // ---- broadcast Xp[:,0..2] for the pairs section ----
  if (wid == 0 && lrow < 3) {
#pragma unroll
    for (int m = 0; m < 4; ++m)
#pragma unroll
      for (int r = 0; r < 4; ++r)
        s012[lrow][m * 16 + kh * 4 + r] = acc[m][0][r];
  }
  __syncthreads();

  // ---- fused epilogue (C/D layout: col = lane&15, row = kh*4 + reg) ----
#pragma unroll
  for (int m = 0; m < 4; ++m) {
#pragma unroll
    for (int n = 0; n < 4; ++n) {
      int c = wid * 64 + n * 16 + lrow;
#pragma unroll
      for (int r = 0; r < 4; ++r) {
        int rl = m * 16 + kh * 4 + r;
        float xp = acc[m][n][r];
        float* rp = out + (size_t)(m0 + rl) * OUTW;
        float p2 = xp * xp;
        rp[1 + c] = xp;
        rp[513 + c] = p2;
        rp[1025 + c] = p2 * xp;
        rp[2049 + c] = sqrtf(fabsf(xp) + 1e-8f);
        if (c == 0) {
          rp[0] = 1.0f;                                  // bias
          rp[1537 + 511] = s012[1][rl] * s012[2][rl];    // pair (1,2)
        } else {
          rp[1537 + c - 1] = s012[0][rl] * xp;           // pair (0,c)
        }
      }
    }
  }
}

// ---------------- fallback path (round-1, no workspace needed) ----------------
#define FBM 128
#define FBN 128
#define FBK 32
#define FPAD 40

__global__ __launch_bounds__(256) void gemm_k(const float* __restrict__ A,
                                              const float* __restrict__ B,
                                              float* __restrict__ out) {
  __shared__ __align__(16) short Asf[FBM][FPAD];
  __shared__ __align__(16) short Bsf[FBN][FPAD];
  const int tid = threadIdx.x;
  const int bx = blockIdx.x;
  const int m0 = (bx >> 2) * FBM;
  const int n0 = (bx & 3) * FBN;
  const int wid = tid >> 6, lane = tid & 63;
  const int wr = wid >> 1, wc = wid & 1;
  const int lrow = lane & 15, kh = lane >> 4;
  f32x4 acc[4][4];
#pragma unroll
  for (int i = 0; i < 4; i++)
#pragma unroll
    for (int j = 0; j < 4; j++) acc[i][j] = (f32x4)0.0f;
  for (int k0 = 0; k0 < KK; k0 += FBK) {
#pragma unroll
    for (int i = 0; i < 4; i++) {
      int fid = i * 256 + tid;
      int ar = fid >> 3, ac = (fid & 7) << 2;
      f32x4 v = *(const f32x4*)(A + (size_t)(m0 + ar) * KK + (k0 + ac));
      s16x4 h;
      h[0] = f2bf(v[0]); h[1] = f2bf(v[1]); h[2] = f2bf(v[2]); h[3] = f2bf(v[3]);
      *(s16x4*)&Asf[ar][ac] = h;
    }
#pragma unroll
    for (int i = 0; i < 4; i++) {
      int fid = i * 256 + tid;
      int br = fid >> 5, bc = (fid & 31) << 2;
      f32x4 v = *(const f32x4*)(B + (size_t)(k0 + br) * NN + (n0 + bc));
#pragma unroll
      for (int j = 0; j < 4; j++) Bsf[bc + j][br] = f2bf(v[j]);
    }
    __syncthreads();
    bf16x8 af[4], bf[4];
#pragma unroll
    for (int m = 0; m < 4; m++) af[m] = *(const bf16x8*)&Asf[wr * 64 + m * 16 + lrow][kh * 8];
#pragma unroll
    for (int n = 0; n < 4; n++) bf[n] = *(const bf16x8*)&Bsf[wc * 64 + n * 16 + lrow][kh * 8];
#pragma unroll
    for (int m = 0; m < 4; m++)
#pragma unroll
      for (int n = 0; n < 4; n++)
        acc[m][n] = __builtin_amdgcn_mfma_f32_16x16x32_bf16(af[m], bf[n], acc[m][n], 0, 0, 0);
    __syncthreads();
  }
#pragma unroll
  for (int m = 0; m < 4; m++)
#pragma unroll
    for (int n = 0; n < 4; n++)
#pragma unroll
      for (int r = 0; r < 4; r++) {
        int row = m0 + wr * 64 + m * 16 + kh * 4 + r;
        int col = n0 + wc * 64 + n * 16 + lrow;
        out[(size_t)row * OUTW + 1 + col] = acc[m][n][r];
      }
}

__global__ __launch_bounds__(512) void epi_k(float* __restrict__ out) {
  const int r = blockIdx.x;
  const int c = threadIdx.x;
  float* row = out + (size_t)r * OUTW;
  __shared__ float s[NN];
  float xp = row[1 + c];
  s[c] = xp;
  __syncthreads();
  float p2 = xp * xp;
  float p3 = p2 * xp;
  float sq = sqrtf(fabsf(xp) + 1e-8f);
  float pr = (c < 511) ? s[0] * s[c + 1] : s[1] * s[2];
  if (c == 0) row[0] = 1.0f;
  row[513 + c] = p2;
  row[1025 + c] = p3;
  row[1537 + c] = pr;
  row[2049 + c] = sq;
}

extern "C" void kernel_launch(void* const* d_in, const int* in_sizes, int n_in,
                              void* d_out, int out_size, void* d_ws, size_t ws_size,
                              hipStream_t stream) {
  const float* X = (const float*)d_in[0];
  const float* P = (const float*)d_in[1];
  float* out = (float*)d_out;
  (void)in_sizes; (void)n_in; (void)out_size;

  if (ws_size >= (size_t)NN * KK * sizeof(short)) {
    short* Bt = (short*)d_ws;
    prep_b<<<dim3(256), dim3(256), 0, stream>>>(P, Bt);
    fused_k<<<dim3(MM / BM), dim3(512), 0, stream>>>(X, Bt, out);
  } else {
    gemm_k<<<dim3(512), dim3(256), 0, stream>>>(X, P, out);
    epi_k<<<dim3(MM), dim3(512), 0, stream>>>(out);
  }
}